// Round 7
// baseline (3770.142 us; speedup 1.0000x reference)
//
#include <hip/hip_runtime.h>
#include <math.h>

#define TS 512
#define NB 64
#define NF 64
#define NE 256
#define NH 512
#define NO 128

#define NGRP 4     // batch groups (16 rows each)
#define NSLC 64    // h-slices per group (8 h-idx each)
#define RPG  16    // rows per group (dense MFMA A: no padding waste)
#define SA   584   // LDS A row stride (bf16 elems): 576 + 8 pad

// ws layout (float words)
#define OFF_WCOMB 0        // 2048*64
#define OFF_BCOMB 131072   // 2048
#define OFF_BUFHI 133120   // 2*64*256 u32 (hi-bf16 pairs)
#define OFF_BUFLO 165888   // 2*64*256 u32 (lo-bf16 pairs)
#define OFF_POOL  198656   // 64*512
#define OFF_FLAGS 231424   // 4*512*64*2 ints (t-indexed, never needs zeroing)

#define FLAGVAL 0x0000000100000001ULL

typedef short bf16x8 __attribute__((ext_vector_type(8)));
typedef short bf16x4 __attribute__((ext_vector_type(4)));
typedef float f32x4 __attribute__((ext_vector_type(4)));
typedef unsigned long long u64;

union F8 { bf16x8 s; unsigned short u[8]; };
union F4 { bf16x4 s; unsigned short u[4]; };
union Q2 { u64 q[2]; bf16x8 v; };

__device__ __forceinline__ unsigned short f2bf(float f) {
    unsigned u = __float_as_uint(f);
    u += 0x7fffu + ((u >> 16) & 1u);
    return (unsigned short)(u >> 16);
}
__device__ __forceinline__ float bf2f(unsigned short h) {
    return __uint_as_float(((unsigned)h) << 16);
}
__device__ __forceinline__ float fast_sigmoid(float v) {
    return 1.f / (1.f + __expf(-v));
}
__device__ __forceinline__ float fast_tanh(float v) {
    return 1.f - 2.f / (1.f + __expf(2.f * v));
}

// W_comb[g][f] = sum_e W_ih[g][e] * W_emb[e][f];  b_comb[g] = W_ih[g]·b_emb + b_ih[g] + b_hh[g]
__global__ __launch_bounds__(256) void k_wcomb(const float* __restrict__ W_emb,
                                               const float* __restrict__ b_emb,
                                               const float* __restrict__ W_ih,
                                               const float* __restrict__ b_ih,
                                               const float* __restrict__ b_hh,
                                               float* __restrict__ W_comb,
                                               float* __restrict__ b_comb) {
    __shared__ float wih[4][NE];
    int g0 = blockIdx.x * 4;
    for (int i = threadIdx.x; i < 4 * NE; i += 256)
        wih[i >> 8][i & 255] = W_ih[(size_t)g0 * NE + i];
    __syncthreads();
    int gl = threadIdx.x >> 6, f = threadIdx.x & 63;
    float acc = 0.f;
    for (int e = 0; e < NE; ++e) acc += wih[gl][e] * W_emb[e * NF + f];
    W_comb[(size_t)(g0 + gl) * NF + f] = acc;
    if (f == 0) {
        float a2 = 0.f;
        for (int e = 0; e < NE; ++e) a2 += wih[gl][e] * b_emb[e];
        b_comb[g0 + gl] = a2 + b_ih[g0 + gl] + b_hh[g0 + gl];
    }
}

// Persistent LSTM recurrence, dense-A MFMA + bypass-atomic exchange.
// 256 WGs = 4 batch-groups (16 rows, dense A) x 64 gate-slices (4 types x 8 h).
// Per WG/step: [16 x 576] @ [576 x 32] via mfma_f32_16x16x32_bf16 split-precision;
// waves = 2 n-tiles x 4 k-chunks (kt {5,5,4,4}); k-partials reduced via LDS.
// Exchange: relaxed agent-scope atomics ONLY (L2-bypass; NO cache-maintenance
// fences on the step path — R6 showed an agent acquire fence costs 5x fetch).
// Publish: per-wave flag words (t-indexed); consume: wave0 ballot-polls 64 u64.
__global__ __launch_bounds__(512, 2) void k_lstm(const float* __restrict__ x,
                                                 const float* __restrict__ W_hh,
                                                 const float* __restrict__ W_comb,
                                                 const float* __restrict__ b_comb,
                                                 unsigned int* __restrict__ bufHI,
                                                 unsigned int* __restrict__ bufLO,
                                                 float* __restrict__ pooled,
                                                 int* __restrict__ flags) {
    const int wg = blockIdx.x;
    const int grp = wg >> 6;           // 0..3
    const int slc = wg & 63;           // 0..63 -> h-idx [8*slc, 8*slc+8)
    const int tid = threadIdx.x;
    const int lane = tid & 63, wave = tid >> 6;
    const int m4 = lane & 15;          // A row (batch) / B col (gate)
    const int qq = lane >> 4;          // quad
    const int nt = wave >> 2;          // n-tile 0..1
    const int kq = wave & 3;           // k-chunk 0..3
    const int kt0 = (kq < 2) ? kq * 5 : 10 + (kq - 2) * 4;
    const int ktn = (kq < 2) ? 5 : 4;

    __shared__ __align__(16) unsigned short hAhi[RPG * SA];
    __shared__ __align__(16) unsigned short hAlo[RPG * SA];
    __shared__ __align__(16) float part[4 * 32 * 20];   // [kq][n_loc][b] pad 16->20
    __shared__ float bcl[32];

    // ---- B-fragments (register-resident, split bf16): this WG's 32 gate-rows ----
    const int n_loc = nt * 16 + m4;    // gate local: type = n_loc>>3, j = n_loc&7
    const int grow = (n_loc >> 3) * NH + slc * 8 + (n_loc & 7);
    F8 bhi[5], blo[5];
    #pragma unroll
    for (int k = 0; k < 5; ++k) {
        if (k < ktn) {
            const int kt = kt0 + k;
            const float* wp = (kt < 16)
                ? W_hh   + (size_t)grow * NH + kt * 32 + qq * 8
                : W_comb + (size_t)grow * NF + (kt - 16) * 32 + qq * 8;
            const float4 w0 = *(const float4*)wp;
            const float4 w1 = *(const float4*)(wp + 4);
            float wf[8] = {w0.x, w0.y, w0.z, w0.w, w1.x, w1.y, w1.z, w1.w};
            #pragma unroll
            for (int e = 0; e < 8; ++e) {
                unsigned short hb = f2bf(wf[e]);
                bhi[k].u[e] = hb;
                blo[k].u[e] = f2bf(wf[e] - bf2f(hb));
            }
        }
    }

    if (tid < 32) bcl[tid] = b_comb[(tid >> 3) * NH + slc * 8 + (tid & 7)];

    // zero h-section of A (t=0 state)
    for (int i = tid; i < RPG * NH; i += 512) {
        int r = i >> 9, c = i & 511;
        hAhi[r * SA + c] = 0;
        hAlo[r * SA + c] = 0;
    }
    // stage x(0) into cols 512..575 (256 threads: r=tid>>4, qx=tid&15)
    float4 xpre = make_float4(0.f, 0.f, 0.f, 0.f);
    if (tid < 256) {
        const int r = tid >> 4, qx = tid & 15;
        const float4 xv = *(const float4*)&x[((size_t)(grp * RPG + r) * TS + 0) * NF + qx * 4];
        float xf[4] = {xv.x, xv.y, xv.z, xv.w};
        F4 phi, plo;
        #pragma unroll
        for (int e = 0; e < 4; ++e) {
            unsigned short hb = f2bf(xf[e]);
            phi.u[e] = hb;
            plo.u[e] = f2bf(xf[e] - bf2f(hb));
        }
        *(bf16x4*)&hAhi[r * SA + NH + qx * 4] = phi.s;
        *(bf16x4*)&hAlo[r * SA + NH + qx * 4] = plo.s;
    }

    float c_reg = 0.f, hsum = 0.f;  // live on tid<128
    __syncthreads();

    for (int t = 0; t < TS; ++t) {
        if (t > 0) {
            // wave 0 polls all 64 producer flag-pairs (bypass loads, no fence)
            if (wave == 0) {
                const u64* fp = (const u64*)(flags + (size_t)(grp * TS + (t - 1)) * NSLC * 2);
                int guard = 0;
                for (;;) {
                    u64 v = __hip_atomic_load(fp + lane, __ATOMIC_RELAXED,
                                              __HIP_MEMORY_SCOPE_AGENT);
                    if (__ballot(v == FLAGVAL) == ~0ull) break;
                    __builtin_amdgcn_s_sleep(1);
                    if (++guard > (1 << 22)) break;  // anti-hang escape
                }
            }
            __builtin_amdgcn_fence(__ATOMIC_ACQUIRE, "workgroup");  // compiler/wg order only
            __syncthreads();  // #0: flags confirmed

            // stage h(t-1): bypass atomic u64 loads -> b128 LDS writes (raw copy)
            {
                const int r = tid & 15, jj = tid >> 4;   // jj 0..31
                const int rowbase = (((t - 1) & 1) * NB + grp * RPG + r) * 128;  // u64 units
                const u64* srcHI = (const u64*)bufHI + rowbase;
                const u64* srcLO = (const u64*)bufLO + rowbase;
                #pragma unroll
                for (int i = 0; i < 2; ++i) {
                    const int j8 = jj + 32 * i;          // 8-elem col chunk
                    Q2 hv, lv;
                    hv.q[0] = __hip_atomic_load(srcHI + 2 * j8,     __ATOMIC_RELAXED, __HIP_MEMORY_SCOPE_AGENT);
                    hv.q[1] = __hip_atomic_load(srcHI + 2 * j8 + 1, __ATOMIC_RELAXED, __HIP_MEMORY_SCOPE_AGENT);
                    lv.q[0] = __hip_atomic_load(srcLO + 2 * j8,     __ATOMIC_RELAXED, __HIP_MEMORY_SCOPE_AGENT);
                    lv.q[1] = __hip_atomic_load(srcLO + 2 * j8 + 1, __ATOMIC_RELAXED, __HIP_MEMORY_SCOPE_AGENT);
                    *(bf16x8*)&hAhi[r * SA + 8 * j8] = hv.v;
                    *(bf16x8*)&hAlo[r * SA + 8 * j8] = lv.v;
                }
            }
            // stage x(t) from prefetch regs
            if (tid < 256) {
                const int r = tid >> 4, qx = tid & 15;
                float xf[4] = {xpre.x, xpre.y, xpre.z, xpre.w};
                F4 phi, plo;
                #pragma unroll
                for (int e = 0; e < 4; ++e) {
                    unsigned short hb = f2bf(xf[e]);
                    phi.u[e] = hb;
                    plo.u[e] = f2bf(xf[e] - bf2f(hb));
                }
                *(bf16x4*)&hAhi[r * SA + NH + qx * 4] = phi.s;
                *(bf16x4*)&hAlo[r * SA + NH + qx * 4] = plo.s;
            }
        }
        // prefetch x(t+1)
        if (t + 1 < TS && tid < 256) {
            const int r = tid >> 4, qx = tid & 15;
            xpre = *(const float4*)&x[((size_t)(grp * RPG + r) * TS + (t + 1)) * NF + qx * 4];
        }
        __syncthreads();  // #1: A ready

        // ---- MFMA: dense [16 x k-chunk] @ [k-chunk x 16], 3 split chains ----
        f32x4 acc0 = {0.f, 0.f, 0.f, 0.f};
        f32x4 acc1 = {0.f, 0.f, 0.f, 0.f};
        f32x4 acc2 = {0.f, 0.f, 0.f, 0.f};
        {
            const int abase = m4 * SA;
            #pragma unroll
            for (int k = 0; k < 5; ++k) {
                if (k < ktn) {
                    const int kt = kt0 + k;
                    const bf16x8 ah = *(const bf16x8*)&hAhi[abase + kt * 32 + qq * 8];
                    const bf16x8 al = *(const bf16x8*)&hAlo[abase + kt * 32 + qq * 8];
                    acc0 = __builtin_amdgcn_mfma_f32_16x16x32_bf16(ah, bhi[k].s, acc0, 0, 0, 0);
                    acc1 = __builtin_amdgcn_mfma_f32_16x16x32_bf16(al, bhi[k].s, acc1, 0, 0, 0);
                    acc2 = __builtin_amdgcn_mfma_f32_16x16x32_bf16(ah, blo[k].s, acc2, 0, 0, 0);
                }
            }
        }
        {
            const f32x4 a = acc0 + acc1 + acc2;
            // D[m=qq*4+e][n=m4] -> part[kq][n_loc][b=qq*4+e] (padded stride 20)
            *(float4*)&part[kq * 640 + n_loc * 20 + qq * 4] = make_float4(a.x, a.y, a.z, a.w);
        }
        __syncthreads();  // #2: partials ready

        // fused epilogue on tid<128 (waves 0,1): j = tid>>4 in 0..7, b = tid&15
        if (tid < 128) {
            const int j = tid >> 4, b = tid & 15;
            float v[4];
            #pragma unroll
            for (int ty = 0; ty < 4; ++ty) {
                const int g2 = ty * 8 + j;
                v[ty] = part[g2 * 20 + b] + part[640 + g2 * 20 + b] +
                        part[1280 + g2 * 20 + b] + part[1920 + g2 * 20 + b] + bcl[g2];
            }
            const float iv = fast_sigmoid(v[0]);
            const float fv = fast_sigmoid(v[1]);
            const float gv = fast_tanh(v[2]);
            const float ov = fast_sigmoid(v[3]);
            c_reg = fv * c_reg + iv * gv;
            const float h = ov * fast_tanh(c_reg);
            hsum += h;
            // split-bf16 pack; pair (j even, j odd) via shfl_xor 16 -> one HI + one LO word
            const unsigned short hb = f2bf(h);
            const unsigned short lb = f2bf(h - bf2f(hb));
            const unsigned int pk = ((unsigned)hb << 16) | lb;
            const unsigned int pp = (unsigned)__shfl_xor((int)pk, 16);
            if ((j & 1) == 0) {
                const int widx = ((t & 1) * NB + grp * RPG + b) * 256 + slc * 4 + (j >> 1);
                __hip_atomic_store(&bufHI[widx], (pp & 0xffff0000u) | (pk >> 16),
                                   __ATOMIC_RELAXED, __HIP_MEMORY_SCOPE_AGENT);
                __hip_atomic_store(&bufLO[widx], (pp << 16) | (pk & 0xffffu),
                                   __ATOMIC_RELAXED, __HIP_MEMORY_SCOPE_AGENT);
            }
            // publish: each writer wave acks its own stores then sets its flag word
            if ((tid & 63) == 0) {
                __asm__ volatile("" ::: "memory");
                __builtin_amdgcn_s_waitcnt(0x0f70);  // vmcnt(0)
                __hip_atomic_store(&flags[((size_t)(grp * TS + t) * NSLC + slc) * 2 + (tid >> 6)],
                                   1, __ATOMIC_RELAXED, __HIP_MEMORY_SCOPE_AGENT);
            }
        }
        // no trailing barrier: next step's poll + barrier #0/#1 cover hazards
    }

    if (tid < 128) {
        const int j = tid >> 4, b = tid & 15;
        pooled[(size_t)(grp * RPG + b) * NH + slc * 8 + j] = hsum * (1.f / TS);
    }
}

// out[b][o] = pooled[b]·W_fc[o] + b_fc[o]
__global__ __launch_bounds__(256) void k_fc(const float* __restrict__ pooled,
                                            const float* __restrict__ W_fc,
                                            const float* __restrict__ b_fc,
                                            float* __restrict__ out) {
    __shared__ float pl[2][NH];
    const int b0 = blockIdx.x * 2;
    for (int i = threadIdx.x; i < 2 * NH; i += 256)
        pl[i >> 9][i & 511] = pooled[(size_t)b0 * NH + i];
    __syncthreads();
    const int o = threadIdx.x & 127, bl = threadIdx.x >> 7;
    const float* wr = W_fc + (size_t)o * NH;
    float acc = 0.f;
    #pragma unroll 4
    for (int k = 0; k < NH; k += 4) {
        const float4 wv = *(const float4*)&wr[k];
        acc += pl[bl][k] * wv.x + pl[bl][k + 1] * wv.y +
               pl[bl][k + 2] * wv.z + pl[bl][k + 3] * wv.w;
    }
    out[(size_t)(b0 + bl) * NO + o] = acc + b_fc[o];
}

extern "C" void kernel_launch(void* const* d_in, const int* in_sizes, int n_in,
                              void* d_out, int out_size, void* d_ws, size_t ws_size,
                              hipStream_t stream) {
    const float* x     = (const float*)d_in[0];
    const float* W_emb = (const float*)d_in[1];
    const float* b_emb = (const float*)d_in[2];
    const float* W_ih  = (const float*)d_in[3];
    const float* W_hh  = (const float*)d_in[4];
    const float* b_ih  = (const float*)d_in[5];
    const float* b_hh  = (const float*)d_in[6];
    const float* W_fc  = (const float*)d_in[7];
    const float* b_fc  = (const float*)d_in[8];
    float* out = (float*)d_out;
    float* ws  = (float*)d_ws;

    float* W_comb = ws + OFF_WCOMB;
    float* b_comb = ws + OFF_BCOMB;
    unsigned int* bufHI = (unsigned int*)(ws + OFF_BUFHI);
    unsigned int* bufLO = (unsigned int*)(ws + OFF_BUFLO);
    float* pooled = ws + OFF_POOL;
    int*   flags  = (int*)(ws + OFF_FLAGS);

    hipLaunchKernelGGL(k_wcomb, dim3(512), dim3(256), 0, stream,
                       W_emb, b_emb, W_ih, b_ih, b_hh, W_comb, b_comb);
    hipLaunchKernelGGL(k_lstm,  dim3(256), dim3(512), 0, stream,
                       x, W_hh, W_comb, b_comb, bufHI, bufLO, pooled, flags);
    hipLaunchKernelGGL(k_fc,    dim3(32),  dim3(256), 0, stream,
                       pooled, W_fc, b_fc, out);
}

// Round 8
// 2375.328 us; speedup vs baseline: 1.5872x; 1.5872x over previous
//
#include <hip/hip_runtime.h>
#include <math.h>

#define TS 512
#define NB 64
#define NF 64
#define NE 256
#define NH 512
#define NO 128

#define NGRP 16    // batch groups (4 rows each)
#define NSLC 16    // h-slices per group (32 h-idx each)
#define RPG  4     // rows per group
#define GPW  128   // gate-rows per WG (4 types x 32 h)
#define NKT  18    // k-tiles of 32 (512 h + 64 x)
#define SA   584   // LDS A row stride (bf16 elems): 576 + 8 pad

// ws layout (float words)
#define OFF_WCOMB 0        // 2048*64
#define OFF_BCOMB 131072   // 2048
#define OFF_HBUF  133120   // u64[2][64][512] tagged h words = 131072 floats
#define OFF_POOL  264192   // 64*512

typedef short bf16x8 __attribute__((ext_vector_type(8)));
typedef short bf16x4 __attribute__((ext_vector_type(4)));
typedef float f32x4 __attribute__((ext_vector_type(4)));
typedef unsigned long long u64;

union F8 { bf16x8 s; unsigned short u[8]; };
union F4 { bf16x4 s; unsigned short u[4]; };

__device__ __forceinline__ unsigned short f2bf(float f) {
    unsigned u = __float_as_uint(f);
    u += 0x7fffu + ((u >> 16) & 1u);
    return (unsigned short)(u >> 16);
}
__device__ __forceinline__ float bf2f(unsigned short h) {
    return __uint_as_float(((unsigned)h) << 16);
}
__device__ __forceinline__ float fast_sigmoid(float v) {
    return 1.f / (1.f + __expf(-v));
}
__device__ __forceinline__ float fast_tanh(float v) {
    return 1.f - 2.f / (1.f + __expf(2.f * v));
}

// W_comb[g][f] = sum_e W_ih[g][e] * W_emb[e][f];  b_comb[g] = W_ih[g]·b_emb + b_ih[g] + b_hh[g]
__global__ __launch_bounds__(256) void k_wcomb(const float* __restrict__ W_emb,
                                               const float* __restrict__ b_emb,
                                               const float* __restrict__ W_ih,
                                               const float* __restrict__ b_ih,
                                               const float* __restrict__ b_hh,
                                               float* __restrict__ W_comb,
                                               float* __restrict__ b_comb) {
    __shared__ float wih[4][NE];
    int g0 = blockIdx.x * 4;
    for (int i = threadIdx.x; i < 4 * NE; i += 256)
        wih[i >> 8][i & 255] = W_ih[(size_t)g0 * NE + i];
    __syncthreads();
    int gl = threadIdx.x >> 6, f = threadIdx.x & 63;
    float acc = 0.f;
    for (int e = 0; e < NE; ++e) acc += wih[gl][e] * W_emb[e * NF + f];
    W_comb[(size_t)(g0 + gl) * NF + f] = acc;
    if (f == 0) {
        float a2 = 0.f;
        for (int e = 0; e < NE; ++e) a2 += wih[gl][e] * b_emb[e];
        b_comb[g0 + gl] = a2 + b_ih[g0 + gl] + b_hh[g0 + gl];
    }
}

// Persistent LSTM recurrence: R5 partition (16 grp x 16 slc) + tagged seqlock
// exchange. h element = atomic u64 {tag = t+1 | bf16hi<<16 | bf16lo}. No flags,
// no fences, no RMW counters: the tag rides inside the datum, so producer
// visibility == data visibility. Double buffer by t&1; produce-after-consume
// gives one-step slack (overwrite-safe). Poison 0xAA != any tag (tags 1..512).
__global__ __launch_bounds__(512, 2) void k_lstm(const float* __restrict__ x,
                                                 const float* __restrict__ W_hh,
                                                 const float* __restrict__ W_comb,
                                                 const float* __restrict__ b_comb,
                                                 u64* __restrict__ hbuf,
                                                 float* __restrict__ pooled) {
    const int wg = blockIdx.x;
    const int grp = wg & 15;
    const int slc = wg >> 4;
    const int tid = threadIdx.x;
    const int lane = tid & 63, wave = tid >> 6;
    const int m4 = lane & 15;          // A row (batch) / B col (gate)
    const int qq = lane >> 4;          // quad

    __shared__ __align__(16) unsigned short hAhi[RPG * SA];
    __shared__ __align__(16) unsigned short hAlo[RPG * SA];
    __shared__ __align__(16) float part[GPW * 4];   // [gate(128)][row(4)]
    __shared__ float bcl[GPW];

    // ---- B-fragments: W_hh (kt 0..15) + W_comb (kt 16..17), split bf16 ----
    // wave covers gates g_loc = wave*16 + m4; B[k][n]: lane n = m4,
    // k = kt*32 + qq*8 + j  (verified layout: R4/R5 passed end-to-end)
    const int g_loc = wave * 16 + m4;
    const int grow = (g_loc >> 5) * NH + slc * 32 + (g_loc & 31);
    F8 bhi[NKT], blo[NKT];
    #pragma unroll
    for (int kt = 0; kt < NKT; ++kt) {
        const float* wp = (kt < 16)
            ? W_hh   + (size_t)grow * NH + kt * 32 + qq * 8
            : W_comb + (size_t)grow * NF + (kt - 16) * 32 + qq * 8;
        const float4 w0 = *(const float4*)wp;
        const float4 w1 = *(const float4*)(wp + 4);
        float wf[8] = {w0.x, w0.y, w0.z, w0.w, w1.x, w1.y, w1.z, w1.w};
        #pragma unroll
        for (int e = 0; e < 8; ++e) {
            unsigned short hb = f2bf(wf[e]);
            bhi[kt].u[e] = hb;
            blo[kt].u[e] = f2bf(wf[e] - bf2f(hb));
        }
    }

    if (tid < GPW) {
        int Rg = (tid >> 5) * NH + slc * 32 + (tid & 31);
        bcl[tid] = b_comb[Rg];
    }
    // zero h-section of A (t=0 state); x-section staged below
    for (int i = tid; i < RPG * NH; i += 512) {
        int r = i >> 9, c = i & 511;
        hAhi[r * SA + c] = 0;
        hAlo[r * SA + c] = 0;
    }
    // stage x(0) into cols 512..575 (wave 7: 64 threads, r = t2>>4, qx = t2&15)
    if (wave == 7) {
        const int t2 = tid - 448, r = t2 >> 4, qx = t2 & 15;
        const float4 xv = *(const float4*)&x[((size_t)(grp * RPG + r) * TS + 0) * NF + qx * 4];
        float xf[4] = {xv.x, xv.y, xv.z, xv.w};
        F4 phi, plo;
        #pragma unroll
        for (int e = 0; e < 4; ++e) {
            unsigned short hb = f2bf(xf[e]);
            phi.u[e] = hb;
            plo.u[e] = f2bf(xf[e] - bf2f(hb));
        }
        *(bf16x4*)&hAhi[r * SA + NH + qx * 4] = phi.s;
        *(bf16x4*)&hAlo[r * SA + NH + qx * 4] = plo.s;
    }

    float c_reg = 0.f, hsum = 0.f;  // live on tid<128
    __syncthreads();

    for (int t = 0; t < TS; ++t) {
        const bool last = (t + 1 == TS);

        // ---- MFMA: [16(4 real) x 576] @ [576 x 16/wave], 3 split chains ----
        f32x4 acc0 = {0.f, 0.f, 0.f, 0.f};
        f32x4 acc1 = {0.f, 0.f, 0.f, 0.f};
        f32x4 acc2 = {0.f, 0.f, 0.f, 0.f};
        {
            const int abase = m4 * SA;
            #pragma unroll
            for (int kt = 0; kt < NKT; ++kt) {
                bf16x8 ah = {0, 0, 0, 0, 0, 0, 0, 0};
                bf16x8 al = {0, 0, 0, 0, 0, 0, 0, 0};
                if (m4 < RPG) {
                    ah = *(const bf16x8*)&hAhi[abase + kt * 32 + qq * 8];
                    al = *(const bf16x8*)&hAlo[abase + kt * 32 + qq * 8];
                }
                acc0 = __builtin_amdgcn_mfma_f32_16x16x32_bf16(ah, bhi[kt].s, acc0, 0, 0, 0);
                acc1 = __builtin_amdgcn_mfma_f32_16x16x32_bf16(al, bhi[kt].s, acc1, 0, 0, 0);
                acc2 = __builtin_amdgcn_mfma_f32_16x16x32_bf16(ah, blo[kt].s, acc2, 0, 0, 0);
            }
        }
        // D rows 0..3 (batch rows) live on quad 0, regs 0..3
        if (lane < 16) {
            const f32x4 a = acc0 + acc1 + acc2;
            *(float4*)&part[(wave * 16 + lane) << 2] = make_float4(a.x, a.y, a.z, a.w);
        }
        __syncthreads();  // #1: partials ready; A fully consumed

        // x(t+1) prefetch issued first (latency hidden under poll)
        float4 xp = make_float4(0.f, 0.f, 0.f, 0.f);
        if (!last && wave == 7) {
            const int t2 = tid - 448, r = t2 >> 4, qx = t2 & 15;
            xp = *(const float4*)&x[((size_t)(grp * RPG + r) * TS + (t + 1)) * NF + qx * 4];
        }

        // ---- fused epilogue on tid<128: r2 = tid&3, j2 = tid>>2 ----
        if (tid < 128) {
            const int r2 = tid & 3, j2 = tid >> 2;
            const float iv = fast_sigmoid(part[0 * 128 + tid] + bcl[0 * 32 + j2]);
            const float fv = fast_sigmoid(part[1 * 128 + tid] + bcl[1 * 32 + j2]);
            const float gv = fast_tanh   (part[2 * 128 + tid] + bcl[2 * 32 + j2]);
            const float ov = fast_sigmoid(part[3 * 128 + tid] + bcl[3 * 32 + j2]);
            c_reg = fv * c_reg + iv * gv;
            const float h = ov * fast_tanh(c_reg);
            hsum += h;
            if (!last) {
                // tagged word: {t+1 | bf16hi | bf16lo}; full-line wave stores
                const unsigned short hb = f2bf(h);
                const unsigned short lb = f2bf(h - bf2f(hb));
                const u64 w = ((u64)(unsigned)(t + 1) << 32) |
                              ((unsigned)hb << 16) | (unsigned)lb;
                __hip_atomic_store(
                    &hbuf[((size_t)(t & 1) * NB + grp * RPG + r2) * NH + slc * 32 + j2],
                    w, __ATOMIC_RELAXED, __HIP_MEMORY_SCOPE_AGENT);
            }
        }

        // ---- stage h(t) for next step: poll own 4 tagged words ----
        if (!last) {
            const int r = tid >> 7, c4 = (tid & 127) << 2;
            const u64* src = hbuf + ((size_t)(t & 1) * NB + grp * RPG + r) * NH + c4;
            const u64 tg = (u64)(unsigned)(t + 1);
            u64 w0, w1, w2, w3;
            int guard = 0;
            for (;;) {
                w0 = __hip_atomic_load(src + 0, __ATOMIC_RELAXED, __HIP_MEMORY_SCOPE_AGENT);
                w1 = __hip_atomic_load(src + 1, __ATOMIC_RELAXED, __HIP_MEMORY_SCOPE_AGENT);
                w2 = __hip_atomic_load(src + 2, __ATOMIC_RELAXED, __HIP_MEMORY_SCOPE_AGENT);
                w3 = __hip_atomic_load(src + 3, __ATOMIC_RELAXED, __HIP_MEMORY_SCOPE_AGENT);
                if (((w0 >> 32) == tg) & ((w1 >> 32) == tg) &
                    ((w2 >> 32) == tg) & ((w3 >> 32) == tg)) break;
                __builtin_amdgcn_s_sleep(2);
                if (++guard > (1 << 20)) break;  // anti-hang escape
            }
            const u64 hiP = ((w0 >> 16) & 0xffffULL)         | (((w1 >> 16) & 0xffffULL) << 16) |
                            (((w2 >> 16) & 0xffffULL) << 32) | (((w3 >> 16) & 0xffffULL) << 48);
            const u64 loP = (w0 & 0xffffULL)         | ((w1 & 0xffffULL) << 16) |
                            ((w2 & 0xffffULL) << 32) | ((w3 & 0xffffULL) << 48);
            *(u64*)&hAhi[r * SA + c4] = hiP;
            *(u64*)&hAlo[r * SA + c4] = loP;

            // stage x(t+1) (wave 7; xp arrived during the poll)
            if (wave == 7) {
                const int t2 = tid - 448, rr = t2 >> 4, qx = t2 & 15;
                float xf[4] = {xp.x, xp.y, xp.z, xp.w};
                F4 phi, plo;
                #pragma unroll
                for (int e = 0; e < 4; ++e) {
                    unsigned short hb = f2bf(xf[e]);
                    phi.u[e] = hb;
                    plo.u[e] = f2bf(xf[e] - bf2f(hb));
                }
                *(bf16x4*)&hAhi[rr * SA + NH + qx * 4] = phi.s;
                *(bf16x4*)&hAlo[rr * SA + NH + qx * 4] = plo.s;
            }
        }
        __syncthreads();  // #2: A(t+1) ready; part safe to rewrite
    }

    if (tid < 128) {
        const int r2 = tid & 3, j2 = tid >> 2;
        pooled[(size_t)(grp * RPG + r2) * NH + slc * 32 + j2] = hsum * (1.f / TS);
    }
}

// out[b][o] = pooled[b]·W_fc[o] + b_fc[o]
__global__ __launch_bounds__(256) void k_fc(const float* __restrict__ pooled,
                                            const float* __restrict__ W_fc,
                                            const float* __restrict__ b_fc,
                                            float* __restrict__ out) {
    __shared__ float pl[2][NH];
    const int b0 = blockIdx.x * 2;
    for (int i = threadIdx.x; i < 2 * NH; i += 256)
        pl[i >> 9][i & 511] = pooled[(size_t)b0 * NH + i];
    __syncthreads();
    const int o = threadIdx.x & 127, bl = threadIdx.x >> 7;
    const float* wr = W_fc + (size_t)o * NH;
    float acc = 0.f;
    #pragma unroll 4
    for (int k = 0; k < NH; k += 4) {
        const float4 wv = *(const float4*)&wr[k];
        acc += pl[bl][k] * wv.x + pl[bl][k + 1] * wv.y +
               pl[bl][k + 2] * wv.z + pl[bl][k + 3] * wv.w;
    }
    out[(size_t)(b0 + bl) * NO + o] = acc + b_fc[o];
}

extern "C" void kernel_launch(void* const* d_in, const int* in_sizes, int n_in,
                              void* d_out, int out_size, void* d_ws, size_t ws_size,
                              hipStream_t stream) {
    const float* x     = (const float*)d_in[0];
    const float* W_emb = (const float*)d_in[1];
    const float* b_emb = (const float*)d_in[2];
    const float* W_ih  = (const float*)d_in[3];
    const float* W_hh  = (const float*)d_in[4];
    const float* b_ih  = (const float*)d_in[5];
    const float* b_hh  = (const float*)d_in[6];
    const float* W_fc  = (const float*)d_in[7];
    const float* b_fc  = (const float*)d_in[8];
    float* out = (float*)d_out;
    float* ws  = (float*)d_ws;

    float* W_comb = ws + OFF_WCOMB;
    float* b_comb = ws + OFF_BCOMB;
    u64*   hbuf   = (u64*)(ws + OFF_HBUF);
    float* pooled = ws + OFF_POOL;

    hipLaunchKernelGGL(k_wcomb, dim3(512), dim3(256), 0, stream,
                       W_emb, b_emb, W_ih, b_ih, b_hh, W_comb, b_comb);
    hipLaunchKernelGGL(k_lstm,  dim3(256), dim3(512), 0, stream,
                       x, W_hh, W_comb, b_comb, hbuf, pooled);
    hipLaunchKernelGGL(k_fc,    dim3(32),  dim3(256), 0, stream,
                       pooled, W_fc, b_fc, out);
}

// Round 9
// 1806.659 us; speedup vs baseline: 2.0868x; 1.3148x over previous
//
#include <hip/hip_runtime.h>
#include <math.h>

#define TS 512
#define NB 64
#define NF 64
#define NE 256
#define NH 512
#define NO 128

#define NGRP 4     // batch groups (16 rows each)
#define NSLC 64    // h-slices per group (8 h-idx each)
#define RPG  16    // rows per group (dense MFMA A)
#define SA   584   // LDS A row stride (bf16): 576 + 8 pad (uniform 8-phase b128)

// ws layout (float words)
#define OFF_WCOMB 0        // 2048*64
#define OFF_BCOMB 131072   // 2048
#define OFF_HBUF  133120   // u32[2][4][64][128] tagged h words = 65536
#define OFF_POOL  198656   // 64*512

typedef short bf16x8 __attribute__((ext_vector_type(8)));
typedef short bf16x4 __attribute__((ext_vector_type(4)));
typedef float f32x4 __attribute__((ext_vector_type(4)));
typedef unsigned long long u64;
typedef unsigned int u32;

union F8 { bf16x8 s; unsigned short u[8]; };
union F4 { bf16x4 s; unsigned short u[4]; };

__device__ __forceinline__ unsigned short f2bf(float f) {
    unsigned u = __float_as_uint(f);
    u += 0x7fffu + ((u >> 16) & 1u);
    return (unsigned short)(u >> 16);
}
__device__ __forceinline__ float bf2f(unsigned short h) {
    return __uint_as_float(((unsigned)h) << 16);
}
__device__ __forceinline__ float fast_sigmoid(float v) {
    return 1.f / (1.f + __expf(-v));
}
__device__ __forceinline__ float fast_tanh(float v) {
    return 1.f - 2.f / (1.f + __expf(2.f * v));
}

// W_comb[g][f] = sum_e W_ih[g][e] * W_emb[e][f];  b_comb[g] = W_ih[g]·b_emb + b_ih[g] + b_hh[g]
__global__ __launch_bounds__(256) void k_wcomb(const float* __restrict__ W_emb,
                                               const float* __restrict__ b_emb,
                                               const float* __restrict__ W_ih,
                                               const float* __restrict__ b_ih,
                                               const float* __restrict__ b_hh,
                                               float* __restrict__ W_comb,
                                               float* __restrict__ b_comb) {
    __shared__ float wih[4][NE];
    int g0 = blockIdx.x * 4;
    for (int i = threadIdx.x; i < 4 * NE; i += 256)
        wih[i >> 8][i & 255] = W_ih[(size_t)g0 * NE + i];
    __syncthreads();
    int gl = threadIdx.x >> 6, f = threadIdx.x & 63;
    float acc = 0.f;
    for (int e = 0; e < NE; ++e) acc += wih[gl][e] * W_emb[e * NF + f];
    W_comb[(size_t)(g0 + gl) * NF + f] = acc;
    if (f == 0) {
        float a2 = 0.f;
        for (int e = 0; e < NE; ++e) a2 += wih[gl][e] * b_emb[e];
        b_comb[g0 + gl] = a2 + b_ih[g0 + gl] + b_hh[g0 + gl];
    }
}

// Persistent LSTM, dense-A MFMA + u32-tagged seqlock exchange.
// 256 WGs = 4 batch-groups (16 rows, dense A [16x576]) x 64 gate-slices
// (4 types x 8 h). Waves = 8 k-chunks, each wave does BOTH 16-gate n-tiles
// (halves LDS A reads). k-partials reduced in LDS (part[8][32][20]).
// Exchange word: {bf16hi<<16 | bf16lo&~3 | tag2}, tag2 = ((t+1)&3)^2 —
// rides inside the datum (no flags/fences/acks). hbuf[(t&1)][grp][slc][j][b]:
// producer waves store 256B contiguous each => full 64B lines, NO RMW (R7 bug).
__global__ __launch_bounds__(512, 2) void k_lstm(const float* __restrict__ x,
                                                 const float* __restrict__ W_hh,
                                                 const float* __restrict__ W_comb,
                                                 const float* __restrict__ b_comb,
                                                 u32* __restrict__ hbuf,
                                                 float* __restrict__ pooled) {
    const int wg = blockIdx.x;
    const int grp = wg & 3;            // 0..3
    const int slc = wg >> 2;           // 0..63 -> h-idx [8*slc, 8*slc+8)
    const int tid = threadIdx.x;
    const int lane = tid & 63, wave = tid >> 6;
    const int m4 = lane & 15;          // A row (batch) / B col (gate)
    const int qq = lane >> 4;          // quad
    // k-chunks: waves 0..5 -> 2 tiles, waves 6,7 -> 3 tiles (epilogue waves light)
    const int ktn = (wave < 6) ? 2 : 3;
    const int kt0 = (wave < 6) ? wave * 2 : 12 + (wave - 6) * 3;

    __shared__ __align__(16) unsigned short hAhi[RPG * SA];
    __shared__ __align__(16) unsigned short hAlo[RPG * SA];
    __shared__ __align__(16) float part[8 * 32 * 20];   // [wave][n_loc][b] pad 20
    __shared__ float bcl[32];

    // ---- B-fragments (split bf16, register-resident): 2 n-tiles x <=3 tiles ----
    F8 bhi[2][3], blo[2][3];
    #pragma unroll
    for (int nt = 0; nt < 2; ++nt) {
        const int n_loc = nt * 16 + m4;
        const int grow = (n_loc >> 3) * NH + slc * 8 + (n_loc & 7);
        #pragma unroll
        for (int k = 0; k < 3; ++k) {
            if (k < ktn) {
                const int kt = kt0 + k;
                const float* wp = (kt < 16)
                    ? W_hh   + (size_t)grow * NH + kt * 32 + qq * 8
                    : W_comb + (size_t)grow * NF + (kt - 16) * 32 + qq * 8;
                const float4 w0 = *(const float4*)wp;
                const float4 w1 = *(const float4*)(wp + 4);
                float wf[8] = {w0.x, w0.y, w0.z, w0.w, w1.x, w1.y, w1.z, w1.w};
                #pragma unroll
                for (int e = 0; e < 8; ++e) {
                    unsigned short hb = f2bf(wf[e]);
                    bhi[nt][k].u[e] = hb;
                    blo[nt][k].u[e] = f2bf(wf[e] - bf2f(hb));
                }
            }
        }
    }

    if (tid < 32) bcl[tid] = b_comb[(tid >> 3) * NH + slc * 8 + (tid & 7)];

    // zero h-section of A (t=0 state): 2048 u64 words
    for (int i = tid; i < 2048; i += 512) {
        const int r = i >> 7, c4 = (i & 127) << 2;
        *(u64*)&hAhi[r * SA + c4] = 0;
        *(u64*)&hAlo[r * SA + c4] = 0;
    }
    // stage x(0) into cols 512..575 (threads 256..511: r = t2>>4, qx = t2&15)
    if (tid >= 256) {
        const int t2 = tid - 256, r = t2 >> 4, qx = t2 & 15;
        const float4 xv = *(const float4*)&x[((size_t)(grp * RPG + r) * TS + 0) * NF + qx * 4];
        float xf[4] = {xv.x, xv.y, xv.z, xv.w};
        F4 phi, plo;
        #pragma unroll
        for (int e = 0; e < 4; ++e) {
            unsigned short hb = f2bf(xf[e]);
            phi.u[e] = hb;
            plo.u[e] = f2bf(xf[e] - bf2f(hb));
        }
        *(bf16x4*)&hAhi[r * SA + NH + qx * 4] = phi.s;
        *(bf16x4*)&hAlo[r * SA + NH + qx * 4] = plo.s;
    }

    float c_reg = 0.f, hsum = 0.f;  // live on tid<128
    __syncthreads();

    for (int t = 0; t < TS; ++t) {
        const bool last = (t + 1 == TS);

        // ---- MFMA: dense [16 x k-chunk] @ [k-chunk x 32], 3 split chains x 2 nt ----
        f32x4 acc[2][3];
        #pragma unroll
        for (int nt = 0; nt < 2; ++nt)
            #pragma unroll
            for (int c = 0; c < 3; ++c) acc[nt][c] = (f32x4){0.f, 0.f, 0.f, 0.f};
        #pragma unroll
        for (int k = 0; k < 3; ++k) {
            if (k < ktn) {
                const int kt = kt0 + k;
                const bf16x8 ah = *(const bf16x8*)&hAhi[m4 * SA + kt * 32 + qq * 8];
                const bf16x8 al = *(const bf16x8*)&hAlo[m4 * SA + kt * 32 + qq * 8];
                #pragma unroll
                for (int nt = 0; nt < 2; ++nt) {
                    acc[nt][0] = __builtin_amdgcn_mfma_f32_16x16x32_bf16(ah, bhi[nt][k].s, acc[nt][0], 0, 0, 0);
                    acc[nt][1] = __builtin_amdgcn_mfma_f32_16x16x32_bf16(al, bhi[nt][k].s, acc[nt][1], 0, 0, 0);
                    acc[nt][2] = __builtin_amdgcn_mfma_f32_16x16x32_bf16(ah, blo[nt][k].s, acc[nt][2], 0, 0, 0);
                }
            }
        }
        #pragma unroll
        for (int nt = 0; nt < 2; ++nt) {
            const f32x4 a = acc[nt][0] + acc[nt][1] + acc[nt][2];
            // D[m=qq*4+e][n=m4] -> part[wave][nt*16+m4][b=qq*4+e]
            *(float4*)&part[wave * 640 + (nt * 16 + m4) * 20 + qq * 4] =
                make_float4(a.x, a.y, a.z, a.w);
        }
        __syncthreads();  // #1: partials ready; hA consumed

        // x(t+1) prefetch (issued before polls; latency hidden)
        float4 xp = make_float4(0.f, 0.f, 0.f, 0.f);
        if (!last && tid >= 256) {
            const int t2 = tid - 256, r = t2 >> 4, qx = t2 & 15;
            xp = *(const float4*)&x[((size_t)(grp * RPG + r) * TS + (t + 1)) * NF + qx * 4];
        }

        const unsigned tg2 = (unsigned)(((t + 1) & 3) ^ 2);
        u32* const slab = hbuf + ((size_t)((t & 1) * NGRP + grp)) * 8192;

        // ---- fused epilogue on tid<128 (waves 0,1): j = tid>>4, b = tid&15 ----
        if (tid < 128) {
            const int j = tid >> 4, b = tid & 15;
            float v[4];
            #pragma unroll
            for (int ty = 0; ty < 4; ++ty) {
                const int n_loc = ty * 8 + j;
                float s = bcl[n_loc];
                #pragma unroll
                for (int w = 0; w < 8; ++w) s += part[w * 640 + n_loc * 20 + b];
                v[ty] = s;
            }
            const float iv = fast_sigmoid(v[0]);
            const float fv = fast_sigmoid(v[1]);
            const float gv = fast_tanh(v[2]);
            const float ov = fast_sigmoid(v[3]);
            c_reg = fv * c_reg + iv * gv;
            const float h = ov * fast_tanh(c_reg);
            hsum += h;
            if (!last) {
                const unsigned short hb = f2bf(h);
                const unsigned short lb = f2bf(h - bf2f(hb));
                const u32 pk = ((u32)hb << 16) | ((u32)lb & 0xFFFCu) | tg2;
                // layout [slc][j][b]: producer offset = slc*128 + j*16 + b = slc*128 + tid
                __hip_atomic_store(&slab[slc * 128 + tid], pk,
                                   __ATOMIC_RELAXED, __HIP_MEMORY_SCOPE_AGENT);
            }
        }

        // ---- stage h(t): all 512 threads, 4 units x 4 tagged words each ----
        if (!last) {
            const int b = tid & 15, unit0 = tid >> 4;  // 0..31
            #pragma unroll
            for (int it = 0; it < 4; ++it) {
                const int uu = unit0 + 32 * it;        // 0..127
                const int uslc = uu >> 1, jj2 = uu & 1;
                const u32* a0 = slab + uslc * 128 + jj2 * 64 + b;
                u32 w0, w1, w2, w3;
                int guard = 0;
                for (;;) {
                    w0 = __hip_atomic_load(a0 + 0,  __ATOMIC_RELAXED, __HIP_MEMORY_SCOPE_AGENT);
                    w1 = __hip_atomic_load(a0 + 16, __ATOMIC_RELAXED, __HIP_MEMORY_SCOPE_AGENT);
                    w2 = __hip_atomic_load(a0 + 32, __ATOMIC_RELAXED, __HIP_MEMORY_SCOPE_AGENT);
                    w3 = __hip_atomic_load(a0 + 48, __ATOMIC_RELAXED, __HIP_MEMORY_SCOPE_AGENT);
                    if (((((w0 & 3) ^ tg2) | ((w1 & 3) ^ tg2)) |
                         (((w2 & 3) ^ tg2) | ((w3 & 3) ^ tg2))) == 0) break;
                    __builtin_amdgcn_s_sleep(1);
                    if (++guard > (1 << 20)) break;  // anti-hang escape
                }
                const u64 hiP = (u64)(w0 >> 16) | ((u64)(w1 >> 16) << 16) |
                                ((u64)(w2 >> 16) << 32) | ((u64)(w3 >> 16) << 48);
                const u64 loP = (u64)(w0 & 0xFFFCu) | ((u64)(w1 & 0xFFFCu) << 16) |
                                ((u64)(w2 & 0xFFFCu) << 32) | ((u64)(w3 & 0xFFFCu) << 48);
                *(u64*)&hAhi[b * SA + uslc * 8 + jj2 * 4] = hiP;
                *(u64*)&hAlo[b * SA + uslc * 8 + jj2 * 4] = loP;
            }
            // stage x(t+1)
            if (tid >= 256) {
                const int t2 = tid - 256, r = t2 >> 4, qx = t2 & 15;
                float xf[4] = {xp.x, xp.y, xp.z, xp.w};
                F4 phi, plo;
                #pragma unroll
                for (int e = 0; e < 4; ++e) {
                    unsigned short hb = f2bf(xf[e]);
                    phi.u[e] = hb;
                    plo.u[e] = f2bf(xf[e] - bf2f(hb));
                }
                *(bf16x4*)&hAhi[r * SA + NH + qx * 4] = phi.s;
                *(bf16x4*)&hAlo[r * SA + NH + qx * 4] = plo.s;
            }
        }
        __syncthreads();  // #2: hA(t+1) ready; part safe to rewrite
    }

    if (tid < 128) {
        const int j = tid >> 4, b = tid & 15;
        pooled[(size_t)(grp * RPG + b) * NH + slc * 8 + j] = hsum * (1.f / TS);
    }
}

// out[b][o] = pooled[b]·W_fc[o] + b_fc[o]
__global__ __launch_bounds__(256) void k_fc(const float* __restrict__ pooled,
                                            const float* __restrict__ W_fc,
                                            const float* __restrict__ b_fc,
                                            float* __restrict__ out) {
    __shared__ float pl[2][NH];
    const int b0 = blockIdx.x * 2;
    for (int i = threadIdx.x; i < 2 * NH; i += 256)
        pl[i >> 9][i & 511] = pooled[(size_t)b0 * NH + i];
    __syncthreads();
    const int o = threadIdx.x & 127, bl = threadIdx.x >> 7;
    const float* wr = W_fc + (size_t)o * NH;
    float acc = 0.f;
    #pragma unroll 4
    for (int k = 0; k < NH; k += 4) {
        const float4 wv = *(const float4*)&wr[k];
        acc += pl[bl][k] * wv.x + pl[bl][k + 1] * wv.y +
               pl[bl][k + 2] * wv.z + pl[bl][k + 3] * wv.w;
    }
    out[(size_t)(b0 + bl) * NO + o] = acc + b_fc[o];
}

extern "C" void kernel_launch(void* const* d_in, const int* in_sizes, int n_in,
                              void* d_out, int out_size, void* d_ws, size_t ws_size,
                              hipStream_t stream) {
    const float* x     = (const float*)d_in[0];
    const float* W_emb = (const float*)d_in[1];
    const float* b_emb = (const float*)d_in[2];
    const float* W_ih  = (const float*)d_in[3];
    const float* W_hh  = (const float*)d_in[4];
    const float* b_ih  = (const float*)d_in[5];
    const float* b_hh  = (const float*)d_in[6];
    const float* W_fc  = (const float*)d_in[7];
    const float* b_fc  = (const float*)d_in[8];
    float* out = (float*)d_out;
    float* ws  = (float*)d_ws;

    float* W_comb = ws + OFF_WCOMB;
    float* b_comb = ws + OFF_BCOMB;
    u32*   hbuf   = (u32*)(ws + OFF_HBUF);
    float* pooled = ws + OFF_POOL;

    hipLaunchKernelGGL(k_wcomb, dim3(512), dim3(256), 0, stream,
                       W_emb, b_emb, W_ih, b_ih, b_hh, W_comb, b_comb);
    hipLaunchKernelGGL(k_lstm,  dim3(256), dim3(512), 0, stream,
                       x, W_hh, W_comb, b_comb, hbuf, pooled);
    hipLaunchKernelGGL(k_fc,    dim3(32),  dim3(256), 0, stream,
                       pooled, W_fc, b_fc, out);
}